// Round 2
// 1018.715 us; speedup vs baseline: 1.0011x; 1.0011x over previous
//
#include <hip/hip_runtime.h>

// Problem constants (from reference)
#define EMBED_DIM 200
#define NUM_WALKS 25
#define NUM_LAYERS 3
#define BATCH 8192

// One wave (64 lanes) per batch element.
//
// Walk indices are staged ONCE per wave into 4 VGPRs via two coalesced int2
// vector loads (lane l<50 holds indices {2l, 2l+1} of the 100-int walk
// block). Each row-gather obtains its wave-uniform index with
// __builtin_amdgcn_readlane (SALU) -- no SMEM loads, no lgkmcnt waits on the
// index path inside the gather loop. Row loads are saddr-form dwordx4
// (SGPR base + shared lane-offset VGPR) and issue back-to-back.
//
// The walk loop is a runtime loop over w (25 iters) with the 3 layers
// unrolled inside: 6 row loads in flight per iteration, small static code
// size. __launch_bounds__(256,4) caps VGPRs at 128 -> >=4 waves/SIMD.
__global__ __launch_bounds__(256, 4) void gnp_score_kernel(
    const float* __restrict__ emb,      // [1e6, 200]
    const float* __restrict__ lw,       // [4] layer weights (pre-softmax)
    const int*   __restrict__ uidx,     // [B]
    const int*   __restrict__ iidx,     // [B]
    const int*   __restrict__ uwalks,   // [B, 25, 4]
    const int*   __restrict__ iwalks,   // [B, 25, 4]
    float*       __restrict__ out)      // [B]
{
    const int lane = threadIdx.x & 63;
    // Wave-uniform batch element, forced into an SGPR.
    const int b = __builtin_amdgcn_readfirstlane(blockIdx.x * 4 + (threadIdx.x >> 6));

    // softmax over 4 layer weights (uniform values; cheap)
    const float l0 = lw[0], l1 = lw[1], l2 = lw[2], l3 = lw[3];
    const float mx = fmaxf(fmaxf(l0, l1), fmaxf(l2, l3));
    const float e0 = expf(l0 - mx), e1 = expf(l1 - mx);
    const float e2 = expf(l2 - mx), e3 = expf(l3 - mx);
    const float inv = 1.0f / (e0 + e1 + e2 + e3);
    const float w0 = e0 * inv;                         // base-row weight
    const float c1 = e1 * inv * (1.0f / NUM_WALKS);    // layer-mean weights / 25
    const float c2 = e2 * inv * (1.0f / NUM_WALKS);
    const float c3 = e3 * inv * (1.0f / NUM_WALKS);

    // Lanes 50..63 alias lane 49's slice (same 16 B -> broadcast, no extra
    // HBM traffic); their contribution is zeroed at the reduction.
    const int dl = (lane < 50) ? lane : 49;
    const unsigned doff = (unsigned)dl * 4u;   // float offset within row

    // ---- Stage ALL walk indices for this element into 4 VGPRs. ----
    const int il2 = (lane < 50) ? lane : 49;
    const int2 vu = *(const int2*)(uwalks + b * 100 + 2 * il2);
    const int2 vi = *(const int2*)(iwalks + b * 100 + 2 * il2);

    float4 au0, ai0, au1, ai1;
    {
        // Base rows (weight w0). uidx[b]/iidx[b] are uniform -> s_load,
        // independent of the staged walk indices.
        const unsigned su = (unsigned)uidx[b];
        const unsigned si = (unsigned)iidx[b];
        const float4 uv = *(const float4*)(emb + (size_t)(su * 200u) + doff);
        const float4 iv = *(const float4*)(emb + (size_t)(si * 200u) + doff);
        au0.x = w0 * uv.x; au0.y = w0 * uv.y; au0.z = w0 * uv.z; au0.w = w0 * uv.w;
        ai0.x = w0 * iv.x; ai0.y = w0 * iv.y; ai0.z = w0 * iv.z; ai0.w = w0 * iv.w;
        au1.x = 0.f; au1.y = 0.f; au1.z = 0.f; au1.w = 0.f;
        ai1.x = 0.f; ai1.y = 0.f; ai1.z = 0.f; ai1.w = 0.f;
    }

    // Walk rows: layers k=1..3 (walks[:, :, 1:]), weight c_k = softmax_k/25.
    // Runtime loop over walks; 3 layers unrolled inside (6 row loads per
    // iteration in flight). readlane lane index = (w*4+k)>>1 is wave-uniform.
    for (int w = 0; w < NUM_WALKS; ++w) {
        const int j1 = w * 4 + 1;  // odd
        const int j2 = w * 4 + 2;  // even
        const int j3 = w * 4 + 3;  // odd
        const unsigned su1 = (unsigned)__builtin_amdgcn_readlane(vu.y, j1 >> 1);
        const unsigned si1 = (unsigned)__builtin_amdgcn_readlane(vi.y, j1 >> 1);
        const unsigned su2 = (unsigned)__builtin_amdgcn_readlane(vu.x, j2 >> 1);
        const unsigned si2 = (unsigned)__builtin_amdgcn_readlane(vi.x, j2 >> 1);
        const unsigned su3 = (unsigned)__builtin_amdgcn_readlane(vu.y, j3 >> 1);
        const unsigned si3 = (unsigned)__builtin_amdgcn_readlane(vi.y, j3 >> 1);

        const float4 uv1 = *(const float4*)(emb + (size_t)(su1 * 200u) + doff);
        const float4 iv1 = *(const float4*)(emb + (size_t)(si1 * 200u) + doff);
        const float4 uv2 = *(const float4*)(emb + (size_t)(su2 * 200u) + doff);
        const float4 iv2 = *(const float4*)(emb + (size_t)(si2 * 200u) + doff);
        const float4 uv3 = *(const float4*)(emb + (size_t)(su3 * 200u) + doff);
        const float4 iv3 = *(const float4*)(emb + (size_t)(si3 * 200u) + doff);

        au0.x = fmaf(c1, uv1.x, au0.x); au0.y = fmaf(c1, uv1.y, au0.y);
        au0.z = fmaf(c1, uv1.z, au0.z); au0.w = fmaf(c1, uv1.w, au0.w);
        ai0.x = fmaf(c1, iv1.x, ai0.x); ai0.y = fmaf(c1, iv1.y, ai0.y);
        ai0.z = fmaf(c1, iv1.z, ai0.z); ai0.w = fmaf(c1, iv1.w, ai0.w);

        au1.x = fmaf(c2, uv2.x, au1.x); au1.y = fmaf(c2, uv2.y, au1.y);
        au1.z = fmaf(c2, uv2.z, au1.z); au1.w = fmaf(c2, uv2.w, au1.w);
        ai1.x = fmaf(c2, iv2.x, ai1.x); ai1.y = fmaf(c2, iv2.y, ai1.y);
        ai1.z = fmaf(c2, iv2.z, ai1.z); ai1.w = fmaf(c2, iv2.w, ai1.w);

        au0.x = fmaf(c3, uv3.x, au0.x); au0.y = fmaf(c3, uv3.y, au0.y);
        au0.z = fmaf(c3, uv3.z, au0.z); au0.w = fmaf(c3, uv3.w, au0.w);
        ai0.x = fmaf(c3, iv3.x, ai0.x); ai0.y = fmaf(c3, iv3.y, ai0.y);
        ai0.z = fmaf(c3, iv3.z, ai0.z); ai0.w = fmaf(c3, iv3.w, ai0.w);
    }

    const float aux = au0.x + au1.x, auy = au0.y + au1.y;
    const float auz = au0.z + au1.z, auw = au0.w + au1.w;
    const float aix = ai0.x + ai1.x, aiy = ai0.y + ai1.y;
    const float aiz = ai0.z + ai1.z, aiw = ai0.w + ai1.w;

    float partial = aux * aix + auy * aiy + auz * aiz + auw * aiw;
    if (lane >= 50) partial = 0.0f;   // drop the aliased lanes

    // Wave-wide sum; all 64 lanes execute.
    #pragma unroll
    for (int off = 32; off > 0; off >>= 1)
        partial += __shfl_xor(partial, off, 64);

    if (lane == 0) out[b] = partial;
}

extern "C" void kernel_launch(void* const* d_in, const int* in_sizes, int n_in,
                              void* d_out, int out_size, void* d_ws, size_t ws_size,
                              hipStream_t stream) {
    const float* emb    = (const float*)d_in[0];
    const float* lw     = (const float*)d_in[1];
    const int*   uidx   = (const int*)d_in[2];
    const int*   iidx   = (const int*)d_in[3];
    const int*   uwalks = (const int*)d_in[4];
    const int*   iwalks = (const int*)d_in[5];
    float*       out    = (float*)d_out;

    // 4 waves (elements) per 256-thread block
    const int blocks = BATCH / 4;  // 2048
    gnp_score_kernel<<<blocks, 256, 0, stream>>>(emb, lw, uidx, iidx,
                                                 uwalks, iwalks, out);
}